// Round 1
// baseline (86.614 us; speedup 1.0000x reference)
//
#include <hip/hip_runtime.h>

#define NFEAT 32
#define NCLS  8
#define NCUT  7   // N_CLASSES - 1

__global__ __launch_bounds__(256) void cloglog_probs_kernel(
    const float* __restrict__ X,
    const float* __restrict__ intercepts,
    const float* __restrict__ beta,
    float* __restrict__ out,
    int n)
{
    __shared__ float s_beta[NFEAT];
    __shared__ float s_cut[NCUT];

    const int t = threadIdx.x;
    if (t < NFEAT) s_beta[t] = beta[t];
    if (t == 0) {
        float c[NCUT];
        #pragma unroll
        for (int a = 0; a < NCUT; ++a) c[a] = intercepts[a];
        // selection sort, 7 elements
        #pragma unroll
        for (int a = 0; a < NCUT; ++a)
            #pragma unroll
            for (int b = a + 1; b < NCUT; ++b)
                if (c[b] < c[a]) { float tmp = c[a]; c[a] = c[b]; c[b] = tmp; }
        #pragma unroll
        for (int a = 0; a < NCUT; ++a) s_cut[a] = c[a];
    }
    __syncthreads();

    // hoist the (uniform) small operands into registers
    float rb[NFEAT];
    #pragma unroll
    for (int j = 0; j < NFEAT; ++j) rb[j] = s_beta[j];
    float cut[NCUT];
    #pragma unroll
    for (int k = 0; k < NCUT; ++k) cut[k] = s_cut[k];

    const long long stride = (long long)gridDim.x * blockDim.x;
    for (long long i = (long long)blockIdx.x * blockDim.x + t; i < n; i += stride) {
        const float4* xp = reinterpret_cast<const float4*>(X + i * NFEAT);
        float eta = 0.f;
        #pragma unroll
        for (int j = 0; j < NFEAT / 4; ++j) {
            float4 v = xp[j];
            eta = fmaf(v.x, rb[4 * j + 0], eta);
            eta = fmaf(v.y, rb[4 * j + 1], eta);
            eta = fmaf(v.z, rb[4 * j + 2], eta);
            eta = fmaf(v.w, rb[4 * j + 3], eta);
        }

        float cum[NCLS];
        #pragma unroll
        for (int k = 0; k < NCUT; ++k) {
            float lp = cut[k] - eta;
            lp = fminf(fmaxf(lp, -30.f), 30.f);
            cum[k] = 1.f - __expf(-__expf(lp));  // cloglog link
        }
        cum[NCUT] = 1.f;

        float p[NCLS];
        p[0] = cum[0];
        #pragma unroll
        for (int k = 1; k < NCLS; ++k) p[k] = cum[k] - cum[k - 1];
        #pragma unroll
        for (int k = 0; k < NCLS; ++k)
            p[k] = fminf(fmaxf(p[k], 1e-9f), 1.f - 1e-9f);

        float4* op = reinterpret_cast<float4*>(out + i * NCLS);
        op[0] = make_float4(p[0], p[1], p[2], p[3]);
        op[1] = make_float4(p[4], p[5], p[6], p[7]);
    }
}

extern "C" void kernel_launch(void* const* d_in, const int* in_sizes, int n_in,
                              void* d_out, int out_size, void* d_ws, size_t ws_size,
                              hipStream_t stream) {
    const float* X          = (const float*)d_in[0];
    const float* intercepts = (const float*)d_in[1];
    const float* beta       = (const float*)d_in[2];
    float* out              = (float*)d_out;

    const int n = in_sizes[0] / NFEAT;  // 2,000,000 rows

    const int block = 256;
    int grid = (n + block - 1) / block;
    if (grid > 2048) grid = 2048;  // grid-stride; ~8 blocks/CU

    cloglog_probs_kernel<<<grid, block, 0, stream>>>(X, intercepts, beta, out, n);
}

// Round 2
// 56.767 us; speedup vs baseline: 1.5258x; 1.5258x over previous
//
#include <hip/hip_runtime.h>

#define NFEAT 32
#define NCLS  8
#define NCUT  7   // N_CLASSES - 1

__global__ __launch_bounds__(256) void cloglog_probs_kernel(
    const float* __restrict__ X,
    const float* __restrict__ intercepts,
    const float* __restrict__ beta,
    float* __restrict__ out,
    long long n)   // number of rows
{
    __shared__ float s_cut[NCUT];

    const int t = threadIdx.x;
    if (t == 0) {
        float c[NCUT];
        #pragma unroll
        for (int a = 0; a < NCUT; ++a) c[a] = intercepts[a];
        // selection sort, 7 elements
        #pragma unroll
        for (int a = 0; a < NCUT; ++a)
            #pragma unroll
            for (int b = a + 1; b < NCUT; ++b)
                if (c[b] < c[a]) { float tmp = c[a]; c[a] = c[b]; c[b] = tmp; }
        #pragma unroll
        for (int a = 0; a < NCUT; ++a) s_cut[a] = c[a];
    }
    __syncthreads();

    const int s = t & 7;          // slot within 8-lane row-group
    // each lane's beta fragment (features 4s..4s+3) — uniform per slot, L1-resident
    const float4 b = reinterpret_cast<const float4*>(beta)[s];
    const float cutv = s_cut[s < NCUT ? s : 0];   // lane 7's value unused

    const long long group   = ((long long)blockIdx.x * blockDim.x + t) >> 3;
    const long long ngroups = ((long long)gridDim.x * blockDim.x) >> 3;

    for (long long row = group; row < n; row += ngroups) {
        // wave-contiguous float4 load: lane i reads index groupBase*8 + i
        const float4 v = reinterpret_cast<const float4*>(X)[row * 8 + s];

        float part = fmaf(v.x, b.x, fmaf(v.y, b.y, fmaf(v.z, b.z, v.w * b.w)));
        // reduce across the 8-lane group -> full dot product eta
        part += __shfl_xor(part, 1, 8);
        part += __shfl_xor(part, 2, 8);
        part += __shfl_xor(part, 4, 8);
        const float eta = part;

        float cum;
        if (s < NCUT) {
            float lp = fminf(fmaxf(cutv - eta, -30.f), 30.f);
            cum = 1.f - __expf(-__expf(lp));   // cloglog link
        } else {
            cum = 1.f;
        }

        // first difference along the class axis
        float prev = __shfl_up(cum, 1, 8);
        if (s == 0) prev = 0.f;
        float p = cum - prev;
        p = fminf(fmaxf(p, 1e-9f), 1.f - 1e-9f);

        out[row * 8 + s] = p;   // wave-contiguous 4B stores
    }
}

extern "C" void kernel_launch(void* const* d_in, const int* in_sizes, int n_in,
                              void* d_out, int out_size, void* d_ws, size_t ws_size,
                              hipStream_t stream) {
    const float* X          = (const float*)d_in[0];
    const float* intercepts = (const float*)d_in[1];
    const float* beta       = (const float*)d_in[2];
    float* out              = (float*)d_out;

    const long long n = (long long)in_sizes[0] / NFEAT;  // 2,000,000 rows

    const int block = 256;                 // 32 rows per block-iteration
    long long groups_needed = (n + 31) / 32;
    int grid = (int)(groups_needed < 2048 ? groups_needed : 2048);  // grid-stride

    cloglog_probs_kernel<<<grid, block, 0, stream>>>(X, intercepts, beta, out, n);
}